// Round 1
// baseline (242.371 us; speedup 1.0000x reference)
//
#include <hip/hip_runtime.h>
#include <cfloat>
#include <math.h>

#define BINS 64
#define NELEM (192*224*192)   // 8,257,536 elements per batch sample (C=1)
#define NB 2
#define HIST_OFF 16           // ws u32 index where final histograms start

// ---- monotonic float<->uint key (unsigned ascending == float ascending) ----
__device__ __forceinline__ unsigned fkey(float f){
    unsigned u = __float_as_uint(f);
    return (u & 0x80000000u) ? ~u : (u | 0x80000000u);
}
__device__ __forceinline__ float funkey(unsigned k){
    unsigned u = (k & 0x80000000u) ? (k ^ 0x80000000u) : ~k;
    return __uint_as_float(u);
}

// ws layout (u32): [0..15] minmax keys: b*4 + {fmin,fmax,wmin,wmax}
//                  [16..16+NB*4096) joint histograms
__global__ void k_init(unsigned* ws){
    int i = blockIdx.x * 256 + threadIdx.x;
    if (i < 16) ws[i] = ((i & 1) == 0) ? 0xFFFFFFFFu : 0u;  // min slots=+inf key, max slots=0
    if (i < NB * BINS * BINS) ws[HIST_OFF + i] = 0u;
}

__global__ void k_minmax(const float* __restrict__ F, const float* __restrict__ W,
                         unsigned* ws){
    const int b = blockIdx.y;
    const float4* F4 = (const float4*)(F + (size_t)b * NELEM);
    const float4* W4 = (const float4*)(W + (size_t)b * NELEM);
    const int n4 = NELEM / 4;
    float fmn = FLT_MAX, fmx = -FLT_MAX, wmn = FLT_MAX, wmx = -FLT_MAX;
    for (int i = blockIdx.x * blockDim.x + threadIdx.x; i < n4;
         i += gridDim.x * blockDim.x){
        float4 a = F4[i], c = W4[i];
        fmn = fminf(fmn, fminf(fminf(a.x, a.y), fminf(a.z, a.w)));
        fmx = fmaxf(fmx, fmaxf(fmaxf(a.x, a.y), fmaxf(a.z, a.w)));
        wmn = fminf(wmn, fminf(fminf(c.x, c.y), fminf(c.z, c.w)));
        wmx = fmaxf(wmx, fmaxf(fmaxf(c.x, c.y), fmaxf(c.z, c.w)));
    }
    // wave(64) butterfly-ish reduce
    for (int off = 32; off; off >>= 1){
        fmn = fminf(fmn, __shfl_down(fmn, off));
        fmx = fmaxf(fmx, __shfl_down(fmx, off));
        wmn = fminf(wmn, __shfl_down(wmn, off));
        wmx = fmaxf(wmx, __shfl_down(wmx, off));
    }
    __shared__ float s[4][4];
    int wave = threadIdx.x >> 6;
    if ((threadIdx.x & 63) == 0){
        s[wave][0] = fmn; s[wave][1] = fmx; s[wave][2] = wmn; s[wave][3] = wmx;
    }
    __syncthreads();
    if (threadIdx.x == 0){
        float a0 = s[0][0], a1 = s[0][1], a2 = s[0][2], a3 = s[0][3];
        for (int wv = 1; wv < 4; ++wv){
            a0 = fminf(a0, s[wv][0]); a1 = fmaxf(a1, s[wv][1]);
            a2 = fminf(a2, s[wv][2]); a3 = fmaxf(a3, s[wv][3]);
        }
        atomicMin(&ws[b*4+0], fkey(a0));
        atomicMax(&ws[b*4+1], fkey(a1));
        atomicMin(&ws[b*4+2], fkey(a2));
        atomicMax(&ws[b*4+3], fkey(a3));
    }
}

__global__ void k_hist(const float* __restrict__ F, const float* __restrict__ W,
                       unsigned* ws){
    const int b = blockIdx.y;
    __shared__ unsigned h[BINS * BINS];
    for (int i = threadIdx.x; i < BINS * BINS; i += blockDim.x) h[i] = 0u;
    __syncthreads();
    const float fmn = funkey(ws[b*4+0]);
    const float fmx = funkey(ws[b*4+1]);
    const float wmn = funkey(ws[b*4+2]);
    const float wmx = funkey(ws[b*4+3]);
    const float fden = fmx - fmn + 1e-10f;   // matches ref f32 arithmetic
    const float wden = wmx - wmn + 1e-10f;
    const float4* F4 = (const float4*)(F + (size_t)b * NELEM);
    const float4* W4 = (const float4*)(W + (size_t)b * NELEM);
    const int n4 = NELEM / 4;
    for (int i = blockIdx.x * blockDim.x + threadIdx.x; i < n4;
         i += gridDim.x * blockDim.x){
        float4 a = F4[i], c = W4[i];
        float fa[4] = {a.x, a.y, a.z, a.w};
        float wa[4] = {c.x, c.y, c.z, c.w};
        #pragma unroll
        for (int k = 0; k < 4; ++k){
            // exact ref order: ((x - xmin) / (xmax - xmin + EPS)) * 63, trunc, clamp
            int fi = (int)((fa[k] - fmn) / fden * 63.0f);
            int wi = (int)((wa[k] - wmn) / wden * 63.0f);
            fi = min(max(fi, 0), 63);
            wi = min(max(wi, 0), 63);
            atomicAdd(&h[fi * BINS + wi], 1u);
        }
    }
    __syncthreads();
    unsigned* gh = ws + HIST_OFF + b * BINS * BINS;
    for (int i = threadIdx.x; i < BINS * BINS; i += blockDim.x){
        unsigned v = h[i];
        if (v) atomicAdd(&gh[i], v);
    }
}

__device__ double block_sum256(double v, double* sred){
    int t = threadIdx.x;
    sred[t] = v; __syncthreads();
    for (int off = 128; off; off >>= 1){
        if (t < off) sred[t] += sred[t + off];
        __syncthreads();
    }
    double r = sred[0]; __syncthreads();
    return r;
}

__global__ void k_final(const float* __restrict__ pa, const float* __restrict__ ta,
                        const unsigned* __restrict__ ws, float* __restrict__ out){
    __shared__ double sred[256];
    const unsigned* hist = ws + HIST_OFF;
    // f32 ref: joint.sum() == N exactly; +1e-10 is a no-op at this magnitude
    const double invN = 1.0 / (double)NELEM;
    double loss_sim = 0.0;
    for (int b = 0; b < NB; ++b){
        const unsigned* H = hist + b * BINS * BINS;
        double hj_p = 0.0;
        for (int i = threadIdx.x; i < BINS * BINS; i += 256){
            double p = (double)H[i] * invN;
            hj_p += p * log(p + 1e-10);
        }
        double hj = -block_sum256(hj_p, sred);
        double hf_p = 0.0, hw_p = 0.0;
        if (threadIdx.x < BINS){
            int r = threadIdx.x;
            double pf = 0.0, pw = 0.0;
            for (int j = 0; j < BINS; ++j){
                pf += (double)H[r * BINS + j];
                pw += (double)H[j * BINS + r];
            }
            pf *= invN; pw *= invN;
            hf_p = pf * log(pf + 1e-10);
            hw_p = pw * log(pw + 1e-10);
        }
        double hf = -block_sum256(hf_p, sred);
        double hw = -block_sum256(hw_p, sred);
        double mi  = hf + hw - hj;
        double nmi = 2.0 * mi / (hf + hw + 1e-10);
        loss_sim += -nmi;
    }
    loss_sim /= (double)NB;
    if (threadIdx.x == 0){
        double a = 0.0;
        for (int i = 0; i < 24; ++i){
            double d = (double)pa[i] - (double)ta[i];
            a += d * d;
        }
        a /= 24.0;
        out[0] = (float)(a + loss_sim);
    }
}

extern "C" void kernel_launch(void* const* d_in, const int* in_sizes, int n_in,
                              void* d_out, int out_size, void* d_ws, size_t ws_size,
                              hipStream_t stream) {
    const float* pa = (const float*)d_in[0];   // predicted_affine (2,12)
    const float* ta = (const float*)d_in[1];   // true_affine      (2,12)
    const float* F  = (const float*)d_in[2];   // fixed  (2,1,192,224,192)
    const float* W  = (const float*)d_in[3];   // warped (2,1,192,224,192)
    float* out = (float*)d_out;
    unsigned* ws = (unsigned*)d_ws;

    k_init<<<dim3(32 + 1), 256, 0, stream>>>(ws);
    k_minmax<<<dim3(512, NB), 256, 0, stream>>>(F, W, ws);
    k_hist<<<dim3(256, NB), 256, 0, stream>>>(F, W, ws);
    k_final<<<1, 256, 0, stream>>>(pa, ta, ws, out);
}